// Round 1
// baseline (524.825 us; speedup 1.0000x reference)
//
#include <hip/hip_runtime.h>
#include <math.h>

// Problem constants (from setup_inputs)
#define BB 1024     // batch
#define LL 50       // sequence length
#define DD 256      // embedding dim
#define TWO_D 512
#define DEG 12      // neighbors per node (adj_rows = repeat(arange(N), DEG))
#define NITER 50    // entmax bisect iterations

__device__ __forceinline__ float wave_sum64(float v) {
#pragma unroll
    for (int off = 32; off > 0; off >>= 1) v += __shfl_xor(v, off, 64);
    return v;
}
__device__ __forceinline__ float wave_max64(float v) {
#pragma unroll
    for (int off = 32; off > 0; off >>= 1) v = fmaxf(v, __shfl_xor(v, off, 64));
    return v;
}

// K1: hidden[bl, d] = 0.5 * (emb[it,d] + sum_k val[it*12+k] * emb[col[it*12+k], d])
__global__ __launch_bounds__(256) void k_gather_conv(
    const int* __restrict__ items, const float* __restrict__ item_emb,
    const int* __restrict__ adj_cols, const float* __restrict__ adj_vals,
    float* __restrict__ hidden)
{
    int bl = blockIdx.x;      // 0 .. B*L-1
    int d  = threadIdx.x;     // 0 .. 255
    int it = items[bl];
    __shared__ int   s_col[DEG];
    __shared__ float s_val[DEG];
    if (d < DEG) {
        s_col[d] = adj_cols[it * DEG + d];
        s_val[d] = adj_vals[it * DEG + d];
    }
    __syncthreads();
    float self = item_emb[it * DD + d];
    float agg = 0.f;
#pragma unroll
    for (int k = 0; k < DEG; ++k)
        agg += s_val[k] * item_emb[s_col[k] * DD + d];
    hidden[bl * DD + d] = 0.5f * (self + agg);
}

// K2: te[b,d] = sum_k tgt[b,k] * wf_w[d,k] + wf_b[d]     (4 batch rows per block)
__global__ __launch_bounds__(256) void k_target(
    const float* __restrict__ tgt, const float* __restrict__ wf_w,
    const float* __restrict__ wf_b, float* __restrict__ te)
{
    const int BPB = 4;
    __shared__ float x_s[BPB * TWO_D];
    int b0 = blockIdx.x * BPB;
    int tid = threadIdx.x;
    for (int i = tid; i < BPB * TWO_D; i += 256) x_s[i] = tgt[b0 * TWO_D + i];
    __syncthreads();
    float bias = wf_b[tid];
    float acc[BPB];
#pragma unroll
    for (int j = 0; j < BPB; ++j) acc[j] = bias;
    const float4* w4 = (const float4*)(wf_w + tid * TWO_D);
    for (int kk = 0; kk < TWO_D / 4; ++kk) {
        float4 w = w4[kk];
#pragma unroll
        for (int j = 0; j < BPB; ++j) {
            const float* xs = x_s + j * TWO_D + kk * 4;
            acc[j] += xs[0] * w.x + xs[1] * w.y + xs[2] * w.z + xs[3] * w.w;
        }
    }
#pragma unroll
    for (int j = 0; j < BPB; ++j) te[(b0 + j) * DD + tid] = acc[j];
}

// K2b: t2[b,d] = sum_k te[b,k] * at_w2[k,d] + at_bias[d]  (4 batch rows per block)
__global__ __launch_bounds__(256) void k_t2(
    const float* __restrict__ te, const float* __restrict__ at_w2,
    const float* __restrict__ at_bias, float* __restrict__ t2)
{
    const int BPB = 4;
    __shared__ float te_s[BPB * DD];
    int b0 = blockIdx.x * BPB;
    int tid = threadIdx.x;
    for (int i = tid; i < BPB * DD; i += 256) te_s[i] = te[b0 * DD + i];
    __syncthreads();
    float bias = at_bias[tid];
    float acc[BPB];
#pragma unroll
    for (int j = 0; j < BPB; ++j) acc[j] = bias;
    for (int k = 0; k < DD; ++k) {
        float w = at_w2[k * DD + tid];   // coalesced across threads
#pragma unroll
        for (int j = 0; j < BPB; ++j) acc[j] += te_s[j * DD + k] * w;
    }
#pragma unroll
    for (int j = 0; j < BPB; ++j) t2[(b0 + j) * DD + tid] = acc[j];
}

// K2c: alpha[b] = sigmoid(dot(te[b], alphaw_w) + alphaw_b) + 1  (==1 -> 1.00001)
__global__ __launch_bounds__(64) void k_alpha(
    const float* __restrict__ te, const float* __restrict__ aw,
    const float* __restrict__ ab, float* __restrict__ alpha)
{
    int b = blockIdx.x;
    int lane = threadIdx.x;
    float s = 0.f;
#pragma unroll
    for (int d = 0; d < DD; d += 64) s += te[b * DD + d + lane] * aw[d + lane];
    s = wave_sum64(s);
    if (lane == 0) {
        float x = s + ab[0];
        float sig = 1.f / (1.f + expf(-x));
        float a = 1.f + sig;
        if (a == 1.f) a = 1.00001f;
        alpha[b] = a;
    }
}

// K3: scores[b,l] = sum_d relu( (hidden[b,l]@at_w1)[d] + t2[b,d] ) * at_w0[d]
// block = 128 threads (2 waves); thread owns columns d0=tid and d1=tid+128.
__global__ __launch_bounds__(128) void k_scores(
    const float* __restrict__ hidden, const float* __restrict__ at_w1,
    const float* __restrict__ t2, const float* __restrict__ at_w0,
    float* __restrict__ scores)
{
    __shared__ __align__(16) float h_s[LL * DD];  // 50 KB
    __shared__ float red_s[2 * LL];
    int b = blockIdx.x;
    int tid = threadIdx.x;

    const float4* hsrc = (const float4*)(hidden + (size_t)b * LL * DD);
    float4* hdst = (float4*)h_s;
    for (int i = tid; i < LL * DD / 4; i += 128) hdst[i] = hsrc[i];
    __syncthreads();

    float acc0[LL], acc1[LL];
#pragma unroll
    for (int l = 0; l < LL; ++l) { acc0[l] = 0.f; acc1[l] = 0.f; }

    int d0 = tid, d1 = tid + 128;
    const float* w1a = at_w1 + d0;
    const float* w1b = at_w1 + d1;
    for (int k4 = 0; k4 < DD / 4; ++k4) {
        int k = k4 * 4;
        float w00 = w1a[(k + 0) * DD], w01 = w1a[(k + 1) * DD];
        float w02 = w1a[(k + 2) * DD], w03 = w1a[(k + 3) * DD];
        float w10 = w1b[(k + 0) * DD], w11 = w1b[(k + 1) * DD];
        float w12 = w1b[(k + 2) * DD], w13 = w1b[(k + 3) * DD];
#pragma unroll
        for (int l = 0; l < LL; ++l) {
            float4 h = ((const float4*)h_s)[l * (DD / 4) + k4];
            acc0[l] += h.x * w00 + h.y * w01 + h.z * w02 + h.w * w03;
            acc1[l] += h.x * w10 + h.y * w11 + h.z * w12 + h.w * w13;
        }
    }

    float t20 = t2[b * DD + d0], t21 = t2[b * DD + d1];
    float wa = at_w0[d0], wb = at_w0[d1];
    int wv = tid >> 6, lane = tid & 63;
#pragma unroll
    for (int l = 0; l < LL; ++l) {
        float v = fmaxf(acc0[l] + t20, 0.f) * wa + fmaxf(acc1[l] + t21, 0.f) * wb;
        v = wave_sum64(v);
        if (lane == 0) red_s[l * 2 + wv] = v;
    }
    __syncthreads();
    if (tid < LL) scores[b * LL + tid] = red_s[tid * 2] + red_s[tid * 2 + 1];
}

// K4: entmax-bisect over L (wave 0), then c[b,d] = sum_l attn[l]*hidden[b,l,d],
//     selu, L2-normalize.
__global__ __launch_bounds__(256) void k_entmax_out(
    const float* __restrict__ scores, const float* __restrict__ alpha,
    const float* __restrict__ hidden, float* __restrict__ out)
{
    __shared__ float attn_s[LL];
    __shared__ float red[4];
    int b = blockIdx.x;
    int tid = threadIdx.x;

    if (tid < 64) {
        int l = tid;
        float a = alpha[b];
        float am1 = a - 1.f;
        float invv = 1.f / am1;
        float x = (l < LL) ? scores[b * LL + l] : -__builtin_inff();
        float Xa = x * am1;

        float mx = wave_max64(Xa);
        float tau_lo = mx - 1.f;
        float tau_hi = mx - powf(1.f / (float)LL, am1);

        float p0 = powf(fmaxf(Xa - tau_lo, 0.f), invv);
        float f_lo = wave_sum64(p0) - 1.f;

        float dm = tau_hi - tau_lo;
        float tau_m = tau_lo;
#pragma unroll 1
        for (int it = 0; it < NITER; ++it) {
            dm *= 0.5f;
            tau_m = tau_lo + dm;
            float pm = powf(fmaxf(Xa - tau_m, 0.f), invv);
            float f_m = wave_sum64(pm) - 1.f;
            if (f_m * f_lo >= 0.f) tau_lo = tau_m;
        }
        float pm = powf(fmaxf(Xa - tau_m, 0.f), invv);
        float s = wave_sum64(pm);
        if (l < LL) attn_s[l] = pm / s;
    }
    __syncthreads();

    int d = tid;
    const float* hb = hidden + (size_t)b * LL * DD;
    float c = 0.f;
#pragma unroll
    for (int l = 0; l < LL; ++l) c += attn_s[l] * hb[l * DD + d];

    // selu (jax constants)
    const float SC = 1.0507009873554805f;
    const float AL = 1.6732632423543772f;
    c = SC * (c > 0.f ? c : AL * expm1f(c));

    // L2 norm over d
    float ss = c * c;
    ss = wave_sum64(ss);
    int wv = tid >> 6, lane = tid & 63;
    if (lane == 0) red[wv] = ss;
    __syncthreads();
    float tot = red[0] + red[1] + red[2] + red[3];
    out[b * DD + d] = c / sqrtf(tot);
}

extern "C" void kernel_launch(void* const* d_in, const int* in_sizes, int n_in,
                              void* d_out, int out_size, void* d_ws, size_t ws_size,
                              hipStream_t stream) {
    const int*   items     = (const int*)  d_in[0];
    // d_in[1] inputs_seq, d_in[2] alias_inputs: unused by the reference
    const float* tgt       = (const float*)d_in[3];
    const float* item_emb  = (const float*)d_in[4];
    // d_in[5] adj_rows: structurally repeat(arange(N), DEG) -> implicit
    const int*   adj_cols  = (const int*)  d_in[6];
    const float* adj_vals  = (const float*)d_in[7];
    const float* wf_w      = (const float*)d_in[8];
    const float* wf_b      = (const float*)d_in[9];
    const float* alphaw_w  = (const float*)d_in[10];
    const float* alphaw_b  = (const float*)d_in[11];
    const float* at_w0     = (const float*)d_in[12];
    const float* at_w1     = (const float*)d_in[13];
    const float* at_w2     = (const float*)d_in[14];
    const float* at_bias   = (const float*)d_in[15];

    float* ws     = (float*)d_ws;
    float* hidden = ws;                                  // B*L*D
    float* te     = hidden + (size_t)BB * LL * DD;       // B*D
    float* t2     = te + (size_t)BB * DD;                // B*D
    float* alpha  = t2 + (size_t)BB * DD;                // B
    float* scores = alpha + BB;                          // B*L
    float* out    = (float*)d_out;

    k_gather_conv<<<BB * LL, 256, 0, stream>>>(items, item_emb, adj_cols, adj_vals, hidden);
    k_target<<<BB / 4, 256, 0, stream>>>(tgt, wf_w, wf_b, te);
    k_t2<<<BB / 4, 256, 0, stream>>>(te, at_w2, at_bias, t2);
    k_alpha<<<BB, 64, 0, stream>>>(te, alphaw_w, alphaw_b, alpha);
    k_scores<<<BB, 128, 0, stream>>>(hidden, at_w1, t2, at_w0, scores);
    k_entmax_out<<<BB, 256, 0, stream>>>(scores, alpha, hidden, out);
}

// Round 2
// 292.498 us; speedup vs baseline: 1.7943x; 1.7943x over previous
//
#include <hip/hip_runtime.h>
#include <hip/hip_bf16.h>
#include <math.h>

#define BB 1024     // batch
#define LL 50       // sequence length
#define DD 256      // embedding dim
#define TWO_D 512
#define DEG 12      // neighbors per node (adj_rows = repeat(arange(N), DEG))
#define NITER 50    // entmax bisect iterations

typedef __attribute__((ext_vector_type(8))) short short8;
typedef __attribute__((ext_vector_type(4))) float floatx4;

__device__ __forceinline__ float wave_sum64(float v) {
#pragma unroll
    for (int off = 32; off > 0; off >>= 1) v += __shfl_xor(v, off, 64);
    return v;
}
__device__ __forceinline__ float wave_max64(float v) {
#pragma unroll
    for (int off = 32; off > 0; off >>= 1) v = fmaxf(v, __shfl_xor(v, off, 64));
    return v;
}

// K1: hidden_bf16[bl,d] = bf16( 0.5*(emb[it,d] + sum_k val*emb[col,d]) )
__global__ __launch_bounds__(256) void k_gather_conv(
    const int* __restrict__ items, const float* __restrict__ item_emb,
    const int* __restrict__ adj_cols, const float* __restrict__ adj_vals,
    __hip_bfloat16* __restrict__ hbf)
{
    int bl = blockIdx.x;
    int d  = threadIdx.x;
    int it = items[bl];
    __shared__ int   s_col[DEG];
    __shared__ float s_val[DEG];
    if (d < DEG) {
        s_col[d] = adj_cols[it * DEG + d];
        s_val[d] = adj_vals[it * DEG + d];
    }
    __syncthreads();
    float self = item_emb[it * DD + d];
    float agg = 0.f;
#pragma unroll
    for (int k = 0; k < DEG; ++k)
        agg += s_val[k] * item_emb[s_col[k] * DD + d];
    hbf[(size_t)bl * DD + d] = __float2bfloat16(0.5f * (self + agg));
}

// Kprep: w1t[n*256+k] = bf16(at_w1[k*256+n])   (transposed bf16 copy of W1)
__global__ __launch_bounds__(256) void k_prep_w1(
    const float* __restrict__ at_w1, ushort* __restrict__ w1t)
{
    __shared__ ushort s[4][DD];
    int k0 = blockIdx.x * 4;
    int n = threadIdx.x;
#pragma unroll
    for (int j = 0; j < 4; ++j) {
        __hip_bfloat16 v = __float2bfloat16(at_w1[(k0 + j) * DD + n]);
        s[j][n] = *(ushort*)&v;
    }
    __syncthreads();
    ushort4 pk;
    pk.x = s[0][n]; pk.y = s[1][n]; pk.z = s[2][n]; pk.w = s[3][n];
    *(ushort4*)(w1t + n * DD + k0) = pk;
}

// K2: te[b,d] = sum_k tgt[b,k] * wf_w[d,k] + wf_b[d]   (4 batch rows per block)
__global__ __launch_bounds__(256) void k_target(
    const float* __restrict__ tgt, const float* __restrict__ wf_w,
    const float* __restrict__ wf_b, float* __restrict__ te)
{
    const int BPB = 4;
    __shared__ float x_s[BPB * TWO_D];
    int b0 = blockIdx.x * BPB;
    int tid = threadIdx.x;
    for (int i = tid; i < BPB * TWO_D; i += 256) x_s[i] = tgt[b0 * TWO_D + i];
    __syncthreads();
    float bias = wf_b[tid];
    float acc[BPB];
#pragma unroll
    for (int j = 0; j < BPB; ++j) acc[j] = bias;
    const float4* w4 = (const float4*)(wf_w + tid * TWO_D);
    for (int kk = 0; kk < TWO_D / 4; ++kk) {
        float4 w = w4[kk];
#pragma unroll
        for (int j = 0; j < BPB; ++j) {
            const float* xs = x_s + j * TWO_D + kk * 4;
            acc[j] += xs[0] * w.x + xs[1] * w.y + xs[2] * w.z + xs[3] * w.w;
        }
    }
#pragma unroll
    for (int j = 0; j < BPB; ++j) te[(b0 + j) * DD + tid] = acc[j];
}

// K2b: t2[b,d] = sum_k te[b,k] * at_w2[k,d] + at_bias[d]
__global__ __launch_bounds__(256) void k_t2(
    const float* __restrict__ te, const float* __restrict__ at_w2,
    const float* __restrict__ at_bias, float* __restrict__ t2)
{
    const int BPB = 4;
    __shared__ float te_s[BPB * DD];
    int b0 = blockIdx.x * BPB;
    int tid = threadIdx.x;
    for (int i = tid; i < BPB * DD; i += 256) te_s[i] = te[b0 * DD + i];
    __syncthreads();
    float bias = at_bias[tid];
    float acc[BPB];
#pragma unroll
    for (int j = 0; j < BPB; ++j) acc[j] = bias;
    for (int k = 0; k < DD; ++k) {
        float w = at_w2[k * DD + tid];
#pragma unroll
        for (int j = 0; j < BPB; ++j) acc[j] += te_s[j * DD + k] * w;
    }
#pragma unroll
    for (int j = 0; j < BPB; ++j) t2[(b0 + j) * DD + tid] = acc[j];
}

// K2c: alpha[b] = sigmoid(dot(te[b], alphaw_w) + alphaw_b) + 1  (==1 -> 1.00001)
__global__ __launch_bounds__(64) void k_alpha(
    const float* __restrict__ te, const float* __restrict__ aw,
    const float* __restrict__ ab, float* __restrict__ alpha)
{
    int b = blockIdx.x;
    int lane = threadIdx.x;
    float s = 0.f;
#pragma unroll
    for (int d = 0; d < DD; d += 64) s += te[b * DD + d + lane] * aw[d + lane];
    s = wave_sum64(s);
    if (lane == 0) {
        float x = s + ab[0];
        float sig = 1.f / (1.f + expf(-x));
        float a = 1.f + sig;
        if (a == 1.f) a = 1.00001f;
        alpha[b] = a;
    }
}

// K3 (MFMA): scores[row] = sum_n relu( (H@W1)[row,n] + t2[b(row),n] ) * w0[n]
// block: 256 thr (4 waves), M=64 rows, N=256 (each wave owns 64 cols), K staged
// in 4 chunks of 64. LDS stride padded to 72 bf16 (144B) -> <=2-way bank alias.
__global__ __launch_bounds__(256) void k_scores_mfma(
    const ushort* __restrict__ hbf, const ushort* __restrict__ w1t,
    const float* __restrict__ t2, const float* __restrict__ at_w0,
    float* __restrict__ scores)
{
    __shared__ __align__(16) ushort sA[64 * 72];    //  9216 B
    __shared__ __align__(16) ushort sB[256 * 72];   // 36864 B
    __shared__ float sred[64][4];
    int tid = threadIdx.x;
    int blk = blockIdx.x;
    int lane = tid & 63, wv = tid >> 6;
    int cn = lane & 15, q = lane >> 4;
    int n0 = wv * 64;
    const size_t rowbase = (size_t)blk * 64;

    floatx4 acc[4][4];
#pragma unroll
    for (int mt = 0; mt < 4; ++mt)
#pragma unroll
        for (int nt = 0; nt < 4; ++nt)
            acc[mt][nt] = (floatx4){0.f, 0.f, 0.f, 0.f};

#pragma unroll 1
    for (int kc = 0; kc < 4; ++kc) {
        // stage A chunk: 64 rows x 64 k (bf16)
#pragma unroll
        for (int it = 0; it < 2; ++it) {
            int i = tid + it * 256;
            int row = i >> 3, seg = i & 7;
            *(uint4*)(sA + row * 72 + seg * 8) =
                *(const uint4*)(hbf + (rowbase + row) * 256 + kc * 64 + seg * 8);
        }
        // stage Bt chunk: 256 n x 64 k (bf16)
#pragma unroll
        for (int it = 0; it < 8; ++it) {
            int i = tid + it * 256;
            int n = i >> 3, seg = i & 7;
            *(uint4*)(sB + n * 72 + seg * 8) =
                *(const uint4*)(w1t + n * 256 + kc * 64 + seg * 8);
        }
        __syncthreads();
#pragma unroll
        for (int ks = 0; ks < 2; ++ks) {
            short8 af[4], bfr[4];
#pragma unroll
            for (int mt = 0; mt < 4; ++mt)
                af[mt] = *(const short8*)(sA + (mt * 16 + cn) * 72 + ks * 32 + q * 8);
#pragma unroll
            for (int nt = 0; nt < 4; ++nt)
                bfr[nt] = *(const short8*)(sB + (n0 + nt * 16 + cn) * 72 + ks * 32 + q * 8);
#pragma unroll
            for (int mt = 0; mt < 4; ++mt)
#pragma unroll
                for (int nt = 0; nt < 4; ++nt)
                    acc[mt][nt] = __builtin_amdgcn_mfma_f32_16x16x32_bf16(
                        af[mt], bfr[nt], acc[mt][nt], 0, 0, 0);
        }
        __syncthreads();
    }

    // epilogue: relu(+t2)*w0, reduce over n
    float w0v[4];
#pragma unroll
    for (int nt = 0; nt < 4; ++nt) w0v[nt] = at_w0[n0 + nt * 16 + cn];
#pragma unroll
    for (int mt = 0; mt < 4; ++mt) {
#pragma unroll
        for (int r = 0; r < 4; ++r) {
            int row_in = q * 4 + r;                       // 0..15
            int row_g = blk * 64 + mt * 16 + row_in;
            int b = row_g / 50;
            const float* t2b = t2 + b * DD;
            float p = 0.f;
#pragma unroll
            for (int nt = 0; nt < 4; ++nt) {
                int col = n0 + nt * 16 + cn;
                float v = acc[mt][nt][r] + t2b[col];
                p += fmaxf(v, 0.f) * w0v[nt];
            }
            p += __shfl_xor(p, 1, 64);
            p += __shfl_xor(p, 2, 64);
            p += __shfl_xor(p, 4, 64);
            p += __shfl_xor(p, 8, 64);
            if (cn == 0) sred[mt * 16 + row_in][wv] = p;
        }
    }
    __syncthreads();
    if (tid < 64)
        scores[blk * 64 + tid] = sred[tid][0] + sred[tid][1] + sred[tid][2] + sred[tid][3];
}

// K4: entmax-bisect over L (wave 0), then c[b,d] = sum_l attn[l]*hidden[b,l,d],
//     selu, L2-normalize.
__global__ __launch_bounds__(256) void k_entmax_out(
    const float* __restrict__ scores, const float* __restrict__ alpha,
    const __hip_bfloat16* __restrict__ hbf, float* __restrict__ out)
{
    __shared__ float attn_s[LL];
    __shared__ float red[4];
    int b = blockIdx.x;
    int tid = threadIdx.x;

    if (tid < 64) {
        int l = tid;
        float a = alpha[b];
        float am1 = a - 1.f;
        float invv = 1.f / am1;
        float x = (l < LL) ? scores[b * LL + l] : -__builtin_inff();
        float Xa = x * am1;

        float mx = wave_max64(Xa);
        float tau_lo = mx - 1.f;
        float tau_hi = mx - powf(1.f / (float)LL, am1);

        float p0 = powf(fmaxf(Xa - tau_lo, 0.f), invv);
        float f_lo = wave_sum64(p0) - 1.f;

        float dm = tau_hi - tau_lo;
        float tau_m = tau_lo;
#pragma unroll 1
        for (int it = 0; it < NITER; ++it) {
            dm *= 0.5f;
            tau_m = tau_lo + dm;
            float pm = powf(fmaxf(Xa - tau_m, 0.f), invv);
            float f_m = wave_sum64(pm) - 1.f;
            if (f_m * f_lo >= 0.f) tau_lo = tau_m;
        }
        float pm = powf(fmaxf(Xa - tau_m, 0.f), invv);
        float s = wave_sum64(pm);
        if (l < LL) attn_s[l] = pm / s;
    }
    __syncthreads();

    int d = tid;
    const __hip_bfloat16* hb = hbf + (size_t)b * LL * DD;
    float c = 0.f;
#pragma unroll
    for (int l = 0; l < LL; ++l) c += attn_s[l] * __bfloat162float(hb[l * DD + d]);

    const float SC = 1.0507009873554805f;
    const float AL = 1.6732632423543772f;
    c = SC * (c > 0.f ? c : AL * expm1f(c));

    float ss = c * c;
    ss = wave_sum64(ss);
    int wv = tid >> 6, lane = tid & 63;
    if (lane == 0) red[wv] = ss;
    __syncthreads();
    float tot = red[0] + red[1] + red[2] + red[3];
    out[b * DD + d] = c / sqrtf(tot);
}

extern "C" void kernel_launch(void* const* d_in, const int* in_sizes, int n_in,
                              void* d_out, int out_size, void* d_ws, size_t ws_size,
                              hipStream_t stream) {
    const int*   items     = (const int*)  d_in[0];
    const float* tgt       = (const float*)d_in[3];
    const float* item_emb  = (const float*)d_in[4];
    const int*   adj_cols  = (const int*)  d_in[6];
    const float* adj_vals  = (const float*)d_in[7];
    const float* wf_w      = (const float*)d_in[8];
    const float* wf_b      = (const float*)d_in[9];
    const float* alphaw_w  = (const float*)d_in[10];
    const float* alphaw_b  = (const float*)d_in[11];
    const float* at_w0     = (const float*)d_in[12];
    const float* at_w1     = (const float*)d_in[13];
    const float* at_w2     = (const float*)d_in[14];
    const float* at_bias   = (const float*)d_in[15];

    // workspace carve (16B-aligned chunks first)
    char* ws = (char*)d_ws;
    ushort* hbf    = (ushort*)ws;                                  // B*L*D bf16
    ws += (size_t)BB * LL * DD * sizeof(ushort);
    ushort* w1t    = (ushort*)ws;                                  // D*D bf16 (transposed)
    ws += (size_t)DD * DD * sizeof(ushort);
    float* te      = (float*)ws;  ws += (size_t)BB * DD * sizeof(float);
    float* t2      = (float*)ws;  ws += (size_t)BB * DD * sizeof(float);
    float* alpha   = (float*)ws;  ws += (size_t)BB * sizeof(float);
    float* scores  = (float*)ws;
    float* out     = (float*)d_out;

    k_gather_conv<<<BB * LL, 256, 0, stream>>>(items, item_emb, adj_cols, adj_vals,
                                               (__hip_bfloat16*)hbf);
    k_prep_w1<<<DD / 4, 256, 0, stream>>>(at_w1, w1t);
    k_target<<<BB / 4, 256, 0, stream>>>(tgt, wf_w, wf_b, te);
    k_t2<<<BB / 4, 256, 0, stream>>>(te, at_w2, at_bias, t2);
    k_alpha<<<BB, 64, 0, stream>>>(te, alphaw_w, alphaw_b, alpha);
    k_scores_mfma<<<(BB * LL) / 64, 256, 0, stream>>>(hbf, w1t, t2, at_w0, scores);
    k_entmax_out<<<BB, 256, 0, stream>>>(scores, alpha, (const __hip_bfloat16*)hbf, out);
}

// Round 4
// 228.680 us; speedup vs baseline: 2.2950x; 1.2791x over previous
//
#include <hip/hip_runtime.h>
#include <hip/hip_bf16.h>
#include <math.h>

#define BB 1024     // batch
#define LL 50       // sequence length
#define DD 256      // embedding dim
#define TWO_D 512
#define NN 40000    // nodes
#define DEG 12      // neighbors per node (adj_rows = repeat(arange(N), DEG))
#define NITER 50    // entmax bisect iterations

typedef __attribute__((ext_vector_type(8))) short short8;
typedef __attribute__((ext_vector_type(4))) float floatx4;

__device__ __forceinline__ float wave_sum64(float v) {
#pragma unroll
    for (int off = 32; off > 0; off >>= 1) v += __shfl_xor(v, off, 64);
    return v;
}
__device__ __forceinline__ float wave_max64(float v) {
#pragma unroll
    for (int off = 32; off > 0; off >>= 1) v = fmaxf(v, __shfl_xor(v, off, 64));
    return v;
}
__device__ __forceinline__ float bf2f(ushort u) {
    union { unsigned int i; float f; } c; c.i = ((unsigned int)u) << 16; return c.f;
}
__device__ __forceinline__ ushort f2bf(float f) {
    __hip_bfloat16 h = __float2bfloat16(f);
    return *(ushort*)&h;
}
// hardware transcendentals: v_exp_f32 (2^x), v_log_f32 (log2 x)
__device__ __forceinline__ float hw_exp2(float x) { return __builtin_amdgcn_exp2f(x); }
__device__ __forceinline__ float hw_log2(float x) { return __builtin_amdgcn_logf(x); }

// K0: ebf = bf16(item_emb), elementwise.
__global__ __launch_bounds__(256) void k_emb_bf16(
    const float* __restrict__ emb, ushort* __restrict__ ebf)
{
    int i = (blockIdx.x * 256 + threadIdx.x) * 4;
    float4 v = *(const float4*)(emb + i);
    ushort4 o;
    o.x = f2bf(v.x); o.y = f2bf(v.y); o.z = f2bf(v.z); o.w = f2bf(v.w);
    *(ushort4*)(ebf + i) = o;
}

// K1a (path A): per-node conv from bf16 table. One wave per node, 4 nodes/block.
// gbf[n,d] = bf16( 0.5*(ebf[n,d] + sum_k val*ebf[col,d]) )
__global__ __launch_bounds__(256) void k_conv_all_bf16(
    const ushort* __restrict__ ebf, const int* __restrict__ adj_cols,
    const float* __restrict__ adj_vals, ushort* __restrict__ gbf)
{
    int wv = threadIdx.x >> 6, lane = threadIdx.x & 63;
    int n = blockIdx.x * 4 + wv;
    int colv = 0; float valv = 0.f;
    if (lane < DEG) { colv = adj_cols[n * DEG + lane]; valv = adj_vals[n * DEG + lane]; }
    ushort4 s = *(const ushort4*)(ebf + (size_t)n * DD + lane * 4);
    float a0 = bf2f(s.x), a1 = bf2f(s.y), a2 = bf2f(s.z), a3 = bf2f(s.w);
#pragma unroll
    for (int k = 0; k < DEG; ++k) {
        int   c = __shfl(colv, k, 64);
        float v = __shfl(valv, k, 64);
        ushort4 e = *(const ushort4*)(ebf + (size_t)c * DD + lane * 4);
        a0 += v * bf2f(e.x); a1 += v * bf2f(e.y);
        a2 += v * bf2f(e.z); a3 += v * bf2f(e.w);
    }
    ushort4 o;
    o.x = f2bf(0.5f * a0); o.y = f2bf(0.5f * a1);
    o.z = f2bf(0.5f * a2); o.w = f2bf(0.5f * a3);
    *(ushort4*)(gbf + (size_t)n * DD + lane * 4) = o;
}

// K1b (path B, small ws): per-node conv straight from fp32 table.
__global__ __launch_bounds__(256) void k_conv_all_f32(
    const float* __restrict__ emb, const int* __restrict__ adj_cols,
    const float* __restrict__ adj_vals, ushort* __restrict__ gbf)
{
    int wv = threadIdx.x >> 6, lane = threadIdx.x & 63;
    int n = blockIdx.x * 4 + wv;
    int colv = 0; float valv = 0.f;
    if (lane < DEG) { colv = adj_cols[n * DEG + lane]; valv = adj_vals[n * DEG + lane]; }
    float4 s = *(const float4*)(emb + (size_t)n * DD + lane * 4);
    float a0 = s.x, a1 = s.y, a2 = s.z, a3 = s.w;
#pragma unroll
    for (int k = 0; k < DEG; ++k) {
        int   c = __shfl(colv, k, 64);
        float v = __shfl(valv, k, 64);
        float4 e = *(const float4*)(emb + (size_t)c * DD + lane * 4);
        a0 += v * e.x; a1 += v * e.y; a2 += v * e.z; a3 += v * e.w;
    }
    ushort4 o;
    o.x = f2bf(0.5f * a0); o.y = f2bf(0.5f * a1);
    o.z = f2bf(0.5f * a2); o.w = f2bf(0.5f * a3);
    *(ushort4*)(gbf + (size_t)n * DD + lane * 4) = o;
}

// Kprep: w1t[n*256+k] = bf16(at_w1[k*256+n])
__global__ __launch_bounds__(256) void k_prep_w1(
    const float* __restrict__ at_w1, ushort* __restrict__ w1t)
{
    __shared__ ushort s[4][DD];
    int k0 = blockIdx.x * 4;
    int n = threadIdx.x;
#pragma unroll
    for (int j = 0; j < 4; ++j) s[j][n] = f2bf(at_w1[(k0 + j) * DD + n]);
    __syncthreads();
    ushort4 pk;
    pk.x = s[0][n]; pk.y = s[1][n]; pk.z = s[2][n]; pk.w = s[3][n];
    *(ushort4*)(w1t + n * DD + k0) = pk;
}

// K2: te[b,d] = sum_k tgt[b,k]*wf_w[d,k] + wf_b[d]
__global__ __launch_bounds__(256) void k_target(
    const float* __restrict__ tgt, const float* __restrict__ wf_w,
    const float* __restrict__ wf_b, float* __restrict__ te)
{
    const int BPB = 4;
    __shared__ float x_s[BPB * TWO_D];
    int b0 = blockIdx.x * BPB;
    int tid = threadIdx.x;
    for (int i = tid; i < BPB * TWO_D; i += 256) x_s[i] = tgt[b0 * TWO_D + i];
    __syncthreads();
    float bias = wf_b[tid];
    float acc[BPB];
#pragma unroll
    for (int j = 0; j < BPB; ++j) acc[j] = bias;
    const float4* w4 = (const float4*)(wf_w + tid * TWO_D);
    for (int kk = 0; kk < TWO_D / 4; ++kk) {
        float4 w = w4[kk];
#pragma unroll
        for (int j = 0; j < BPB; ++j) {
            const float* xs = x_s + j * TWO_D + kk * 4;
            acc[j] += xs[0] * w.x + xs[1] * w.y + xs[2] * w.z + xs[3] * w.w;
        }
    }
#pragma unroll
    for (int j = 0; j < BPB; ++j) te[(b0 + j) * DD + tid] = acc[j];
}

// K2b: t2[b,d] = sum_k te[b,k]*at_w2[k,d] + at_bias[d]
__global__ __launch_bounds__(256) void k_t2(
    const float* __restrict__ te, const float* __restrict__ at_w2,
    const float* __restrict__ at_bias, float* __restrict__ t2)
{
    const int BPB = 4;
    __shared__ float te_s[BPB * DD];
    int b0 = blockIdx.x * BPB;
    int tid = threadIdx.x;
    for (int i = tid; i < BPB * DD; i += 256) te_s[i] = te[b0 * DD + i];
    __syncthreads();
    float bias = at_bias[tid];
    float acc[BPB];
#pragma unroll
    for (int j = 0; j < BPB; ++j) acc[j] = bias;
    for (int k = 0; k < DD; ++k) {
        float w = at_w2[k * DD + tid];
#pragma unroll
        for (int j = 0; j < BPB; ++j) acc[j] += te_s[j * DD + k] * w;
    }
#pragma unroll
    for (int j = 0; j < BPB; ++j) t2[(b0 + j) * DD + tid] = acc[j];
}

// K2c: alpha[b]
__global__ __launch_bounds__(64) void k_alpha(
    const float* __restrict__ te, const float* __restrict__ aw,
    const float* __restrict__ ab, float* __restrict__ alpha)
{
    int b = blockIdx.x;
    int lane = threadIdx.x;
    float s = 0.f;
#pragma unroll
    for (int d = 0; d < DD; d += 64) s += te[b * DD + d + lane] * aw[d + lane];
    s = wave_sum64(s);
    if (lane == 0) {
        float x = s + ab[0];
        float sig = 1.f / (1.f + expf(-x));
        float a = 1.f + sig;
        if (a == 1.f) a = 1.00001f;
        alpha[b] = a;
    }
}

// K3 (MFMA): scores[row] = sum_n relu( (H@W1)[row,n] + t2[b,n] ) * w0[n]
// A rows gathered on the fly: H[row] = gbf[items[row]].
__global__ __launch_bounds__(256) void k_scores_mfma(
    const int* __restrict__ items, const ushort* __restrict__ gbf,
    const ushort* __restrict__ w1t, const float* __restrict__ t2,
    const float* __restrict__ at_w0, float* __restrict__ scores)
{
    __shared__ __align__(16) ushort sA[64 * 72];    //  9216 B
    __shared__ __align__(16) ushort sB[256 * 72];   // 36864 B
    __shared__ float sred[64][4];
    __shared__ int s_items[64];
    int tid = threadIdx.x;
    int blk = blockIdx.x;
    int lane = tid & 63, wv = tid >> 6;
    int cn = lane & 15, q = lane >> 4;
    int n0 = wv * 64;

    if (tid < 64) s_items[tid] = items[blk * 64 + tid];
    __syncthreads();

    floatx4 acc[4][4];
#pragma unroll
    for (int mt = 0; mt < 4; ++mt)
#pragma unroll
        for (int nt = 0; nt < 4; ++nt)
            acc[mt][nt] = (floatx4){0.f, 0.f, 0.f, 0.f};

#pragma unroll 1
    for (int kc = 0; kc < 4; ++kc) {
#pragma unroll
        for (int it = 0; it < 2; ++it) {
            int i = tid + it * 256;
            int row = i >> 3, seg = i & 7;
            *(uint4*)(sA + row * 72 + seg * 8) =
                *(const uint4*)(gbf + (size_t)s_items[row] * DD + kc * 64 + seg * 8);
        }
#pragma unroll
        for (int it = 0; it < 8; ++it) {
            int i = tid + it * 256;
            int n = i >> 3, seg = i & 7;
            *(uint4*)(sB + n * 72 + seg * 8) =
                *(const uint4*)(w1t + n * DD + kc * 64 + seg * 8);
        }
        __syncthreads();
#pragma unroll
        for (int ks = 0; ks < 2; ++ks) {
            short8 af[4], bfr[4];
#pragma unroll
            for (int mt = 0; mt < 4; ++mt)
                af[mt] = *(const short8*)(sA + (mt * 16 + cn) * 72 + ks * 32 + q * 8);
#pragma unroll
            for (int nt = 0; nt < 4; ++nt)
                bfr[nt] = *(const short8*)(sB + (n0 + nt * 16 + cn) * 72 + ks * 32 + q * 8);
#pragma unroll
            for (int mt = 0; mt < 4; ++mt)
#pragma unroll
                for (int nt = 0; nt < 4; ++nt)
                    acc[mt][nt] = __builtin_amdgcn_mfma_f32_16x16x32_bf16(
                        af[mt], bfr[nt], acc[mt][nt], 0, 0, 0);
        }
        __syncthreads();
    }

    float w0v[4];
#pragma unroll
    for (int nt = 0; nt < 4; ++nt) w0v[nt] = at_w0[n0 + nt * 16 + cn];
#pragma unroll
    for (int mt = 0; mt < 4; ++mt) {
#pragma unroll
        for (int r = 0; r < 4; ++r) {
            int row_in = q * 4 + r;
            int row_g = blk * 64 + mt * 16 + row_in;
            int b = row_g / LL;
            const float* t2b = t2 + b * DD;
            float p = 0.f;
#pragma unroll
            for (int nt = 0; nt < 4; ++nt) {
                int col = n0 + nt * 16 + cn;
                float v = acc[mt][nt][r] + t2b[col];
                p += fmaxf(v, 0.f) * w0v[nt];
            }
            p += __shfl_xor(p, 1, 64);
            p += __shfl_xor(p, 2, 64);
            p += __shfl_xor(p, 4, 64);
            p += __shfl_xor(p, 8, 64);
            if (cn == 0) sred[mt * 16 + row_in][wv] = p;
        }
    }
    __syncthreads();
    if (tid < 64)
        scores[blk * 64 + tid] = sred[tid][0] + sred[tid][1] + sred[tid][2] + sred[tid][3];
}

__device__ __forceinline__ float pw(float z, float invv) {
    // z^invv for z>=0, invv>0.  log2(0)=-inf -> exp2(-inf)=0, correct limit.
    return hw_exp2(invv * hw_log2(z));
}

// K4: entmax-bisect over L (wave 0), then c[b,d] = sum_l attn[l]*H[b,l,d],
//     selu, L2-normalize.  H rows gathered: gbf[items[b,l]].
__global__ __launch_bounds__(256) void k_entmax_out(
    const float* __restrict__ scores, const float* __restrict__ alpha,
    const int* __restrict__ items, const ushort* __restrict__ gbf,
    float* __restrict__ out)
{
    __shared__ float attn_s[LL];
    __shared__ int s_it[LL];
    __shared__ float red[4];
    int b = blockIdx.x;
    int tid = threadIdx.x;

    if (tid >= 192 && tid < 192 + LL) s_it[tid - 192] = items[b * LL + (tid - 192)];

    if (tid < 64) {
        int l = tid;
        float a = alpha[b];
        float am1 = a - 1.f;
        float invv = 1.f / am1;
        float x = (l < LL) ? scores[b * LL + l] : -__builtin_inff();
        float Xa = x * am1;

        float mx = wave_max64(Xa);
        float tau_lo = mx - 1.f;
        float tau_hi = mx - hw_exp2(am1 * hw_log2(1.f / (float)LL));

        float f_lo = wave_sum64(pw(fmaxf(Xa - tau_lo, 0.f), invv)) - 1.f;

        float dm = tau_hi - tau_lo;
        float tau_m = tau_lo;
#pragma unroll 1
        for (int it = 0; it < NITER; ++it) {
            dm *= 0.5f;
            tau_m = tau_lo + dm;
            float f_m = wave_sum64(pw(fmaxf(Xa - tau_m, 0.f), invv)) - 1.f;
            if (f_m * f_lo >= 0.f) tau_lo = tau_m;
        }
        float pm = pw(fmaxf(Xa - tau_m, 0.f), invv);
        float s = wave_sum64(pm);
        if (l < LL) attn_s[l] = pm / s;
    }
    __syncthreads();

    int d = tid;
    float c = 0.f;
#pragma unroll
    for (int l = 0; l < LL; ++l)
        c += attn_s[l] * bf2f(gbf[(size_t)s_it[l] * DD + d]);

    const float SC = 1.0507009873554805f;
    const float AL = 1.6732632423543772f;
    c = SC * (c > 0.f ? c : AL * expm1f(c));

    float ss = wave_sum64(c * c);
    int wv = tid >> 6, lane = tid & 63;
    if (lane == 0) red[wv] = ss;
    __syncthreads();
    float tot = red[0] + red[1] + red[2] + red[3];
    out[b * DD + d] = c / sqrtf(tot);
}

extern "C" void kernel_launch(void* const* d_in, const int* in_sizes, int n_in,
                              void* d_out, int out_size, void* d_ws, size_t ws_size,
                              hipStream_t stream) {
    const int*   items     = (const int*)  d_in[0];
    const float* tgt       = (const float*)d_in[3];
    const float* item_emb  = (const float*)d_in[4];
    const int*   adj_cols  = (const int*)  d_in[6];
    const float* adj_vals  = (const float*)d_in[7];
    const float* wf_w      = (const float*)d_in[8];
    const float* wf_b      = (const float*)d_in[9];
    const float* alphaw_w  = (const float*)d_in[10];
    const float* alphaw_b  = (const float*)d_in[11];
    const float* at_w0     = (const float*)d_in[12];
    const float* at_w1     = (const float*)d_in[13];
    const float* at_w2     = (const float*)d_in[14];
    const float* at_bias   = (const float*)d_in[15];

    const size_t SZ_TAB = (size_t)NN * DD * sizeof(ushort);      // 20.48 MB
    char* ws = (char*)d_ws;
    ushort* gbf = (ushort*)ws;   ws += SZ_TAB;                   // conv output (bf16)
    ushort* w1t   = (ushort*)ws; ws += (size_t)DD * DD * sizeof(ushort);
    float* te     = (float*)ws;  ws += (size_t)BB * DD * sizeof(float);
    float* t2     = (float*)ws;  ws += (size_t)BB * DD * sizeof(float);
    float* alpha  = (float*)ws;  ws += ((size_t)BB + 32) * sizeof(float);
    float* scores = (float*)ws;  ws += (size_t)BB * LL * sizeof(float);
    ushort* ebf   = (ushort*)ws; ws += SZ_TAB;                   // bf16 emb table (path A)
    float* out    = (float*)d_out;

    size_t needA = (size_t)(ws - (char*)d_ws);
    bool pathA = ws_size >= needA;

    if (pathA) {
        k_emb_bf16<<<NN * DD / (256 * 4), 256, 0, stream>>>(item_emb, ebf);
        k_conv_all_bf16<<<NN / 4, 256, 0, stream>>>(ebf, adj_cols, adj_vals, gbf);
    } else {
        k_conv_all_f32<<<NN / 4, 256, 0, stream>>>(item_emb, adj_cols, adj_vals, gbf);
    }
    k_prep_w1<<<DD / 4, 256, 0, stream>>>(at_w1, w1t);
    k_target<<<BB / 4, 256, 0, stream>>>(tgt, wf_w, wf_b, te);
    k_t2<<<BB / 4, 256, 0, stream>>>(te, at_w2, at_bias, t2);
    k_alpha<<<BB, 64, 0, stream>>>(te, alphaw_w, alphaw_b, alpha);
    k_scores_mfma<<<(BB * LL) / 64, 256, 0, stream>>>(items, gbf, w1t, t2, at_w0, scores);
    k_entmax_out<<<BB, 256, 0, stream>>>(scores, alpha, items, gbf, out);
}